// Round 7
// baseline (548.866 us; speedup 1.0000x reference)
//
#include <hip/hip_runtime.h>

#define T_STEPS 4096
#define BATCH   2048
#define HID     10
#define UB      16   // steps per buffer; outer loop advances 2*UB (ping-pong)

// DPP row rotate-right by N within each 16-lane row: lane n receives the
// value from lane (n-N)&15. Encoding 0x120|N = row_ror:N (HW-verified R2-R5).
template<int N>
__device__ __forceinline__ float ror16(float v) {
    int r = __builtin_amdgcn_update_dpp(
        0, __builtin_bit_cast(int, v), 0x120 | N, 0xF, 0xF, false);
    return __builtin_bit_cast(float, r);
}

// tanh(a) = 1 - 2/(exp2(C*a)+1), C = 2*log2(e). Saturates at +/-inf;
// tanh_fast(0)==0 exactly (idle lanes stay 0). HW-verified R5.
__device__ __forceinline__ float tanh_fast(float a) {
    float e = __builtin_amdgcn_exp2f(a * 2.88539008177792681472f);
    float r = __builtin_amdgcn_rcpf(e + 1.0f);
    return fmaf(-2.0f, r, 1.0f);
}

// Issue 16 fire-and-forget loads. Volatile asm: cannot be sunk/deleted;
// dest VGPRs stay allocated (they are live until the binding wait below).
__device__ __forceinline__ void issue16(float (&xr)[UB], const float* base) {
#pragma unroll
    for (int u = 0; u < UB; ++u)
        asm volatile("global_load_dword %0, %1, off"
                     : "=v"(xr[u]) : "v"(base + (size_t)u * BATCH));
}

// Wait + rebind: one asm that performs the s_waitcnt AND ties all 16 buffer
// registers as in-outs. This keeps them allocated from issue through the wait
// (no async-clobber reuse — R6's crash), and re-defines them so no consumer
// can be scheduled above the wait. vmcnt(1) tolerates the newest outstanding
// VMEM op (the previous block's out-store); retirement is in-order (m135).
#define BIND16(a) "+v"(a[0]),"+v"(a[1]),"+v"(a[2]),"+v"(a[3]),"+v"(a[4]), \
    "+v"(a[5]),"+v"(a[6]),"+v"(a[7]),"+v"(a[8]),"+v"(a[9]),"+v"(a[10]),   \
    "+v"(a[11]),"+v"(a[12]),"+v"(a[13]),"+v"(a[14]),"+v"(a[15])
__device__ __forceinline__ void wait1_bind(float (&xr)[UB]) {
    asm volatile("s_waitcnt vmcnt(1)" : BIND16(xr) :: "memory");
}
__device__ __forceinline__ void wait0_bind(float (&xr)[UB]) {
    asm volatile("s_waitcnt vmcnt(0)" : BIND16(xr) :: "memory");
}

__global__ __launch_bounds__(64, 1) void rnn_kernel(
    const float* __restrict__ x,
    const float* __restrict__ h0,
    const float* __restrict__ W_ih,
    const float* __restrict__ b_ih,
    const float* __restrict__ W_hh,
    const float* __restrict__ b_hh,
    const float* __restrict__ W_out,
    const float* __restrict__ b_out,
    float* __restrict__ out)
{
    const int tid = threadIdx.x;            // 0..63
    const int j   = tid & 15;               // lane-in-group; j<10 owns h_j
    const int b   = (blockIdx.x << 2) + (tid >> 4);
    const bool jv = (j < HID);
    const int jc  = jv ? j : 0;

    // Per-lane constants; idle lanes (j>=10) get zero weights so h stays 0.
    const float wih  = jv ? W_ih[jc] : 0.0f;
    const float bj   = jv ? (b_ih[jc] + b_hh[jc]) : 0.0f;
    const float wo_j = jv ? W_out[jc] : 0.0f;
    const float bo   = b_out[0];

    // Pre-permuted W_hh row: wsh[N] pairs with ror16<N>(h) = h[(j-N)&15].
    float wsh[16];
#pragma unroll
    for (int N = 0; N < 16; ++N) {
        const int k = (j - N) & 15;
        wsh[N] = (jv && k < HID) ? W_hh[jc * HID + k] : 0.0f;
    }

    float hval = jv ? h0[b * HID + jc] : 0.0f;

    const float* xb = x + b;
    float xA[UB], xB[UB];

    // Prologue: issue block 0 into xA and drain fully once (~1 HBM latency,
    // paid once per kernel).
    issue16(xA, xb);
    wait0_bind(xA);

    for (int t0 = 0; t0 < T_STEPS; t0 += 2 * UB) {
        // ---- half 1: consume xA, prefetch xB(t0+UB) ----
        wait1_bind(xA);                       // no-op count-wise at t0=0
        issue16(xB, xb + (size_t)(t0 + UB) * BATCH);

        float pkeep = 0.0f;
#pragma unroll
        for (int u = 0; u < UB; ++u) {
            float c0 = fmaf(wih, xA[u], bj);
            c0 = fmaf(wsh[0], hval, c0);
            c0 = fmaf(wsh[1], ror16<1>(hval), c0);
            c0 = fmaf(wsh[2], ror16<2>(hval), c0);
            c0 = fmaf(wsh[3], ror16<3>(hval), c0);
            float c1 = wsh[4] * ror16<4>(hval);
            c1 = fmaf(wsh[5], ror16<5>(hval), c1);
            c1 = fmaf(wsh[6], ror16<6>(hval), c1);
            c1 = fmaf(wsh[7], ror16<7>(hval), c1);
            float c2 = wsh[8] * ror16<8>(hval);
            c2 = fmaf(wsh[9],  ror16<9>(hval),  c2);
            c2 = fmaf(wsh[10], ror16<10>(hval), c2);
            c2 = fmaf(wsh[11], ror16<11>(hval), c2);
            float c3 = wsh[12] * ror16<12>(hval);
            c3 = fmaf(wsh[13], ror16<13>(hval), c3);
            c3 = fmaf(wsh[14], ror16<14>(hval), c3);
            c3 = fmaf(wsh[15], ror16<15>(hval), c3);
            hval = tanh_fast((c0 + c1) + (c2 + c3));

            float p = wo_j * hval;
            p += ror16<8>(p);
            p += ror16<4>(p);
            p += ror16<2>(p);
            p += ror16<1>(p);
            if (j == u) pkeep = p;
        }
        out[(size_t)(t0 + j) * BATCH + b] = pkeep + bo;

        // ---- half 2: consume xB, prefetch xA(t0+2*UB) ----
        wait1_bind(xB);   // outstanding: 16 xB loads + the store above (newest)
        const float* xsrc = (t0 + 2 * UB < T_STEPS)
                          ? (xb + (size_t)(t0 + 2 * UB) * BATCH) : xb;
        issue16(xA, xsrc);

        pkeep = 0.0f;
#pragma unroll
        for (int u = 0; u < UB; ++u) {
            float c0 = fmaf(wih, xB[u], bj);
            c0 = fmaf(wsh[0], hval, c0);
            c0 = fmaf(wsh[1], ror16<1>(hval), c0);
            c0 = fmaf(wsh[2], ror16<2>(hval), c0);
            c0 = fmaf(wsh[3], ror16<3>(hval), c0);
            float c1 = wsh[4] * ror16<4>(hval);
            c1 = fmaf(wsh[5], ror16<5>(hval), c1);
            c1 = fmaf(wsh[6], ror16<6>(hval), c1);
            c1 = fmaf(wsh[7], ror16<7>(hval), c1);
            float c2 = wsh[8] * ror16<8>(hval);
            c2 = fmaf(wsh[9],  ror16<9>(hval),  c2);
            c2 = fmaf(wsh[10], ror16<10>(hval), c2);
            c2 = fmaf(wsh[11], ror16<11>(hval), c2);
            float c3 = wsh[12] * ror16<12>(hval);
            c3 = fmaf(wsh[13], ror16<13>(hval), c3);
            c3 = fmaf(wsh[14], ror16<14>(hval), c3);
            c3 = fmaf(wsh[15], ror16<15>(hval), c3);
            hval = tanh_fast((c0 + c1) + (c2 + c3));

            float p = wo_j * hval;
            p += ror16<8>(p);
            p += ror16<4>(p);
            p += ror16<2>(p);
            p += ror16<1>(p);
            if (j == u) pkeep = p;
        }
        out[(size_t)(t0 + UB + j) * BATCH + b] = pkeep + bo;
    }

    // Epilogue: the last half-iteration issued a speculative xA reload that is
    // never consumed. Drain it WHILE its registers are still bound (R6 died
    // here: dead asm-load dest regs got reused, then the in-flight load
    // clobbered them on completion).
    wait0_bind(xA);

    // h_last: lane j holds h_T[j]
    if (jv) out[(size_t)T_STEPS * BATCH + (size_t)b * HID + j] = hval;
}

extern "C" void kernel_launch(void* const* d_in, const int* in_sizes, int n_in,
                              void* d_out, int out_size, void* d_ws, size_t ws_size,
                              hipStream_t stream) {
    const float* x     = (const float*)d_in[0];
    const float* h0    = (const float*)d_in[1];
    const float* W_ih  = (const float*)d_in[2];
    const float* b_ih  = (const float*)d_in[3];
    const float* W_hh  = (const float*)d_in[4];
    const float* b_hh  = (const float*)d_in[5];
    const float* W_out = (const float*)d_in[6];
    const float* b_out = (const float*)d_in[7];

    rnn_kernel<<<BATCH / 4, 64, 0, stream>>>(
        x, h0, W_ih, b_ih, W_hh, b_hh, W_out, b_out, (float*)d_out);
}

// Round 8
// 371.277 us; speedup vs baseline: 1.4783x; 1.4783x over previous
//
#include <hip/hip_runtime.h>

#define T_STEPS 4096
#define BATCH   2048
#define HID     10
#define UB      16   // steps per buffer; outer loop advances 2*UB (ping-pong)

// ---- R7-proven load skeleton ---------------------------------------------
// Volatile-asm loads: cannot be sunk; dest VGPRs pinned live until the
// binding wait. "memory" clobber keeps the out[] stores from migrating
// across the issue point (vmcnt ordering depends on program order).
__device__ __forceinline__ void issue16(float (&xr)[UB], const float* base) {
#pragma unroll
    for (int u = 0; u < UB; ++u)
        asm volatile("global_load_dword %0, %1, off"
                     : "=v"(xr[u]) : "v"(base + (size_t)u * BATCH) : "memory");
}
#define BIND16(a) "+v"(a[0]),"+v"(a[1]),"+v"(a[2]),"+v"(a[3]),"+v"(a[4]), \
    "+v"(a[5]),"+v"(a[6]),"+v"(a[7]),"+v"(a[8]),"+v"(a[9]),"+v"(a[10]),   \
    "+v"(a[11]),"+v"(a[12]),"+v"(a[13]),"+v"(a[14]),"+v"(a[15])
__device__ __forceinline__ void wait1_bind(float (&xr)[UB]) {
    asm volatile("s_waitcnt vmcnt(1)" : BIND16(xr) :: "memory");
}
__device__ __forceinline__ void wait0_bind(float (&xr)[UB]) {
    asm volatile("s_waitcnt vmcnt(0)" : BIND16(xr) :: "memory");
}

// ---- hand-scheduled RNN step ---------------------------------------------
// One step = 31 instrs + 2 nops, exact. Entry: h = h_t, p = wo*h_t (prev
// step's un-reduced out-partial), pk = accumulated kept outputs.
// Does: (a) 16-term dot via DPP-folded fmac (rotation on src0),
//       (b) pipelined 4-level rotation all-reduce of the PREVIOUS step's p
//           (slots 3/6/9/12, each >=2 slots after p's last write - DPP
//           read-after-VALU-write needs 2 wait states),
//       (c) tanh = 1-2/(exp2(C*a)+1) with literal/inline consts,
//       (d) p = wo*h_new for the next step's pipelined reduce (last instr).
// m = keep-mask for the reduce completing here (1.0 on the keep lane).
__device__ __forceinline__ void step_blob(float& h, float& p, float& pk,
                                          float x, float wih, float bj,
                                          float wo, float m,
                                          const float (&w)[16]) {
    float c0, c1;
    asm volatile(
        "v_fma_f32 %[c0], %[wih], %[x], %[bj]\n\t"                            // 1
        "v_mul_f32_dpp %[c1], %[h], %[w4] row_ror:4 row_mask:0xf bank_mask:0xf\n\t" // 2 (h written 2 slots back)
        "v_add_f32_dpp %[p], %[p], %[p] row_ror:8 row_mask:0xf bank_mask:0xf\n\t"   // 3 (p written 2 slots back)
        "v_fmac_f32 %[c0], %[h], %[w0]\n\t"                                   // 4
        "v_fmac_f32_dpp %[c0], %[h], %[w1] row_ror:1 row_mask:0xf bank_mask:0xf\n\t"  // 5
        "v_add_f32_dpp %[p], %[p], %[p] row_ror:4 row_mask:0xf bank_mask:0xf\n\t"     // 6
        "v_fmac_f32_dpp %[c1], %[h], %[w5] row_ror:5 row_mask:0xf bank_mask:0xf\n\t"  // 7
        "v_fmac_f32_dpp %[c0], %[h], %[w2] row_ror:2 row_mask:0xf bank_mask:0xf\n\t"  // 8
        "v_add_f32_dpp %[p], %[p], %[p] row_ror:2 row_mask:0xf bank_mask:0xf\n\t"     // 9
        "v_fmac_f32_dpp %[c1], %[h], %[w6] row_ror:6 row_mask:0xf bank_mask:0xf\n\t"  // 10
        "v_fmac_f32_dpp %[c0], %[h], %[w3] row_ror:3 row_mask:0xf bank_mask:0xf\n\t"  // 11
        "v_add_f32_dpp %[p], %[p], %[p] row_ror:1 row_mask:0xf bank_mask:0xf\n\t"     // 12
        "v_fmac_f32_dpp %[c1], %[h], %[w7] row_ror:7 row_mask:0xf bank_mask:0xf\n\t"  // 13
        "v_fmac_f32_dpp %[c0], %[h], %[w8] row_ror:8 row_mask:0xf bank_mask:0xf\n\t"  // 14
        "v_fmac_f32 %[pk], %[p], %[m]\n\t"                                    // 15 (plain read, interlocked)
        "v_fmac_f32_dpp %[c1], %[h], %[w9] row_ror:9 row_mask:0xf bank_mask:0xf\n\t"  // 16
        "v_fmac_f32_dpp %[c0], %[h], %[w10] row_ror:10 row_mask:0xf bank_mask:0xf\n\t" // 17
        "v_fmac_f32_dpp %[c1], %[h], %[w11] row_ror:11 row_mask:0xf bank_mask:0xf\n\t" // 18
        "v_fmac_f32_dpp %[c0], %[h], %[w12] row_ror:12 row_mask:0xf bank_mask:0xf\n\t" // 19
        "v_fmac_f32_dpp %[c1], %[h], %[w13] row_ror:13 row_mask:0xf bank_mask:0xf\n\t" // 20
        "v_fmac_f32_dpp %[c0], %[h], %[w14] row_ror:14 row_mask:0xf bank_mask:0xf\n\t" // 21
        "v_fmac_f32_dpp %[c1], %[h], %[w15] row_ror:15 row_mask:0xf bank_mask:0xf\n\t" // 22
        "v_add_f32 %[c0], %[c0], %[c1]\n\t"                                   // 23
        "v_mul_f32 %[c0], 0x4038aa3b, %[c0]\n\t"                              // 24  a *= 2*log2(e)
        "v_exp_f32 %[c0], %[c0]\n\t"                                          // 25
        "s_nop 0\n\t"                                                         // trans-use wait state
        "v_add_f32 %[c0], 1.0, %[c0]\n\t"                                     // 26
        "v_rcp_f32 %[c0], %[c0]\n\t"                                          // 27
        "s_nop 0\n\t"                                                         // trans-use wait state
        "v_fma_f32 %[h], -2.0, %[c0], 1.0\n\t"                                // 28  h = 1 - 2*r
        "v_mul_f32 %[p], %[wo], %[h]"                                         // 29  next reduce seed
        : [c0]"=&v"(c0), [c1]"=&v"(c1), [h]"+v"(h), [p]"+v"(p), [pk]"+v"(pk)
        : [x]"v"(x), [wih]"v"(wih), [bj]"v"(bj), [wo]"v"(wo), [m]"v"(m),
          [w0]"v"(w[0]),  [w1]"v"(w[1]),  [w2]"v"(w[2]),  [w3]"v"(w[3]),
          [w4]"v"(w[4]),  [w5]"v"(w[5]),  [w6]"v"(w[6]),  [w7]"v"(w[7]),
          [w8]"v"(w[8]),  [w9]"v"(w[9]),  [w10]"v"(w[10]),[w11]"v"(w[11]),
          [w12]"v"(w[12]),[w13]"v"(w[13]),[w14]"v"(w[14]),[w15]"v"(w[15]));
}

// Block-end finisher: reduce the last step's p (s_nop 1 = 2 wait states
// covers the DPP read-after-write hazards; the compiler's hazard recognizer
// can't see inside asm, so we pad manually).
__device__ __forceinline__ void finish_reduce(float& p, float& pk, float m15) {
    asm volatile(
        "s_nop 1\n\t"
        "v_add_f32_dpp %[p], %[p], %[p] row_ror:8 row_mask:0xf bank_mask:0xf\n\t"
        "s_nop 1\n\t"
        "v_add_f32_dpp %[p], %[p], %[p] row_ror:4 row_mask:0xf bank_mask:0xf\n\t"
        "s_nop 1\n\t"
        "v_add_f32_dpp %[p], %[p], %[p] row_ror:2 row_mask:0xf bank_mask:0xf\n\t"
        "s_nop 1\n\t"
        "v_add_f32_dpp %[p], %[p], %[p] row_ror:1 row_mask:0xf bank_mask:0xf\n\t"
        "v_fmac_f32 %[pk], %[p], %[m]"
        : [p]"+v"(p), [pk]"+v"(pk)
        : [m]"v"(m15));
}

__global__ __launch_bounds__(64, 1) void rnn_kernel(
    const float* __restrict__ x,
    const float* __restrict__ h0,
    const float* __restrict__ W_ih,
    const float* __restrict__ b_ih,
    const float* __restrict__ W_hh,
    const float* __restrict__ b_hh,
    const float* __restrict__ W_out,
    const float* __restrict__ b_out,
    float* __restrict__ out)
{
    const int tid = threadIdx.x;            // 0..63
    const int j   = tid & 15;               // lane-in-group; j<10 owns h_j
    const int b   = (blockIdx.x << 2) + (tid >> 4);
    const bool jv = (j < HID);
    const int jc  = jv ? j : 0;

    // Per-lane constants; idle lanes (j>=10) get zero weights so h stays 0
    // (tanh path: exp2(0)=1, rcp(2)=0.5, 1-2*0.5=0 exactly).
    const float wih  = jv ? W_ih[jc] : 0.0f;
    const float bj   = jv ? (b_ih[jc] + b_hh[jc]) : 0.0f;
    const float wo_j = jv ? W_out[jc] : 0.0f;
    const float bo   = b_out[0];

    // Pre-permuted W_hh row: w[N] pairs with row_ror:N (h[(j-N)&15] -> lane j).
    float wsh[16];
#pragma unroll
    for (int N = 0; N < 16; ++N) {
        const int k = (j - N) & 15;
        wsh[N] = (jv && k < HID) ? W_hh[jc * HID + k] : 0.0f;
    }

    // Keep-masks: km[i] = 1.0 iff this lane keeps the reduce for in-block row i.
    float km[16];
#pragma unroll
    for (int i = 0; i < 16; ++i) km[i] = (j == i) ? 1.0f : 0.0f;
    const float mzero = 0.0f;

    float hval = jv ? h0[b * HID + jc] : 0.0f;
    float p = 0.0f, pk = 0.0f;

    const float* xb = x + b;
    float xA[UB], xB[UB];

    issue16(xA, xb);
    wait0_bind(xA);

    for (int t0 = 0; t0 < T_STEPS; t0 += 2 * UB) {
        // ---- half 1: consume xA, prefetch xB ----
        wait1_bind(xA);
        issue16(xB, xb + (size_t)(t0 + UB) * BATCH);
#pragma unroll
        for (int u = 0; u < UB; ++u)
            step_blob(hval, p, pk, xA[u], wih, bj, wo_j,
                      (u == 0) ? mzero : km[u - 1], wsh);
        finish_reduce(p, pk, km[15]);
        out[(size_t)(t0 + j) * BATCH + b] = pk + bo;   // rows t0..t0+15
        pk = 0.0f;

        // ---- half 2: consume xB, prefetch xA ----
        wait1_bind(xB);
        const float* xsrc = (t0 + 2 * UB < T_STEPS)
                          ? (xb + (size_t)(t0 + 2 * UB) * BATCH) : xb;
        issue16(xA, xsrc);
#pragma unroll
        for (int u = 0; u < UB; ++u)
            step_blob(hval, p, pk, xB[u], wih, bj, wo_j,
                      (u == 0) ? mzero : km[u - 1], wsh);
        finish_reduce(p, pk, km[15]);
        out[(size_t)(t0 + UB + j) * BATCH + b] = pk + bo;
        pk = 0.0f;
    }

    // Drain the final speculative xA reload while its registers are still
    // bound (async-clobber hazard, R6 post-mortem).
    wait0_bind(xA);

    // h_last: lane j holds h_T[j]
    if (jv) out[(size_t)T_STEPS * BATCH + (size_t)b * HID + j] = hval;
}

extern "C" void kernel_launch(void* const* d_in, const int* in_sizes, int n_in,
                              void* d_out, int out_size, void* d_ws, size_t ws_size,
                              hipStream_t stream) {
    const float* x     = (const float*)d_in[0];
    const float* h0    = (const float*)d_in[1];
    const float* W_ih  = (const float*)d_in[2];
    const float* b_ih  = (const float*)d_in[3];
    const float* W_hh  = (const float*)d_in[4];
    const float* b_hh  = (const float*)d_in[5];
    const float* W_out = (const float*)d_in[6];
    const float* b_out = (const float*)d_in[7];

    rnn_kernel<<<BATCH / 4, 64, 0, stream>>>(
        x, h0, W_ih, b_ih, W_hh, b_hh, W_out, b_out, (float*)d_out);
}

// Round 9
// 362.003 us; speedup vs baseline: 1.5162x; 1.0256x over previous
//
#include <hip/hip_runtime.h>

#define T_STEPS 4096
#define BATCH   2048
#define HID     10
#define UB      16   // steps per buffer; outer loop advances 2*UB (ping-pong)

// ---- R7/R8-proven load skeleton ------------------------------------------
__device__ __forceinline__ void issue16(float (&xr)[UB], const float* base) {
#pragma unroll
    for (int u = 0; u < UB; ++u)
        asm volatile("global_load_dword %0, %1, off"
                     : "=v"(xr[u]) : "v"(base + (size_t)u * BATCH) : "memory");
}
#define BIND16(a) "+v"(a[0]),"+v"(a[1]),"+v"(a[2]),"+v"(a[3]),"+v"(a[4]), \
    "+v"(a[5]),"+v"(a[6]),"+v"(a[7]),"+v"(a[8]),"+v"(a[9]),"+v"(a[10]),   \
    "+v"(a[11]),"+v"(a[12]),"+v"(a[13]),"+v"(a[14]),"+v"(a[15])
__device__ __forceinline__ void wait1_bind(float (&xr)[UB]) {
    asm volatile("s_waitcnt vmcnt(1)" : BIND16(xr) :: "memory");
}
__device__ __forceinline__ void wait0_bind(float (&xr)[UB]) {
    asm volatile("s_waitcnt vmcnt(0)" : BIND16(xr) :: "memory");
}

// ---- hand-scheduled RNN step, r-form (27 VALU + 2 nops) -------------------
// State r = 1/(exp2(C*a)+1)  (h = 1-2r folded into weights):
//   a'_t = bj2 + wih2*x_t + sum_N w2[N]*ror_N(r)   [w2=-2C*w, bj2=C*(bj+sum w)]
//   r_{t+1} = rcp(exp2(a'_t) + 1)
// Output pipelined one step behind: slot 2 seeds p = wo2*r_t (out row t-1),
// reduce at slots 6/9/12/15 (spacing 3 covers DPP read-after-write), keep at
// slot 18 with mask m. Entry: r = r_t. Exit: r = r_{t+1}.
// At 4 cyc/instr wave-issue cadence, dependent VALU at adjacent slots is the
// normal full-rate case; only trans (exp/rcp) consumers need a wait state
// (s_nop 0, scalar-pipe, cheap) — R8-proven.
__device__ __forceinline__ void step_blob(float& r, float& p, float& pk,
                                          float x, float wih2, float bj2,
                                          float wo2, float m,
                                          const float (&w)[16]) {
    float c0, c1;
    asm volatile(
        "v_fma_f32 %[c0], %[wih2], %[x], %[bj2]\n\t"                          // 1
        "v_mul_f32 %[p], %[wo2], %[r]\n\t"                                    // 2  seed (r from prev rcp, 1 slot + nop gap)
        "v_mul_f32_dpp %[c1], %[r], %[w4] row_ror:4 row_mask:0xf bank_mask:0xf\n\t"   // 3
        "v_fmac_f32 %[c0], %[r], %[w0]\n\t"                                   // 4
        "v_fmac_f32_dpp %[c1], %[r], %[w5] row_ror:5 row_mask:0xf bank_mask:0xf\n\t"  // 5
        "v_add_f32_dpp %[p], %[p], %[p] row_ror:8 row_mask:0xf bank_mask:0xf\n\t"     // 6
        "v_fmac_f32_dpp %[c0], %[r], %[w1] row_ror:1 row_mask:0xf bank_mask:0xf\n\t"  // 7
        "v_fmac_f32_dpp %[c1], %[r], %[w6] row_ror:6 row_mask:0xf bank_mask:0xf\n\t"  // 8
        "v_add_f32_dpp %[p], %[p], %[p] row_ror:4 row_mask:0xf bank_mask:0xf\n\t"     // 9
        "v_fmac_f32_dpp %[c0], %[r], %[w2] row_ror:2 row_mask:0xf bank_mask:0xf\n\t"  // 10
        "v_fmac_f32_dpp %[c1], %[r], %[w7] row_ror:7 row_mask:0xf bank_mask:0xf\n\t"  // 11
        "v_add_f32_dpp %[p], %[p], %[p] row_ror:2 row_mask:0xf bank_mask:0xf\n\t"     // 12
        "v_fmac_f32_dpp %[c0], %[r], %[w3] row_ror:3 row_mask:0xf bank_mask:0xf\n\t"  // 13
        "v_fmac_f32_dpp %[c1], %[r], %[w8] row_ror:8 row_mask:0xf bank_mask:0xf\n\t"  // 14
        "v_add_f32_dpp %[p], %[p], %[p] row_ror:1 row_mask:0xf bank_mask:0xf\n\t"     // 15
        "v_fmac_f32_dpp %[c0], %[r], %[w10] row_ror:10 row_mask:0xf bank_mask:0xf\n\t" // 16
        "v_fmac_f32_dpp %[c1], %[r], %[w9] row_ror:9 row_mask:0xf bank_mask:0xf\n\t"   // 17
        "v_fmac_f32 %[pk], %[p], %[m]\n\t"                                    // 18 keep (p final at 15)
        "v_fmac_f32_dpp %[c0], %[r], %[w12] row_ror:12 row_mask:0xf bank_mask:0xf\n\t" // 19
        "v_fmac_f32_dpp %[c1], %[r], %[w11] row_ror:11 row_mask:0xf bank_mask:0xf\n\t" // 20
        "v_fmac_f32_dpp %[c0], %[r], %[w14] row_ror:14 row_mask:0xf bank_mask:0xf\n\t" // 21
        "v_fmac_f32_dpp %[c1], %[r], %[w13] row_ror:13 row_mask:0xf bank_mask:0xf\n\t" // 22
        "v_fmac_f32_dpp %[c0], %[r], %[w15] row_ror:15 row_mask:0xf bank_mask:0xf\n\t" // 23
        "v_add_f32 %[c0], %[c0], %[c1]\n\t"                                   // 24
        "v_exp_f32 %[c0], %[c0]\n\t"                                          // 25
        "s_nop 0\n\t"                                                         // trans-use wait state
        "v_add_f32 %[c0], 1.0, %[c0]\n\t"                                     // 26
        "v_rcp_f32 %[r], %[c0]\n\t"                                           // 27  r_{t+1}
        "s_nop 0"                                                             // trans-use wait state (next blob slot 2 reads r)
        : [c0]"=&v"(c0), [c1]"=&v"(c1), [r]"+v"(r), [p]"+v"(p), [pk]"+v"(pk)
        : [x]"v"(x), [wih2]"v"(wih2), [bj2]"v"(bj2), [wo2]"v"(wo2), [m]"v"(m),
          [w0]"v"(w[0]),  [w1]"v"(w[1]),  [w2]"v"(w[2]),  [w3]"v"(w[3]),
          [w4]"v"(w[4]),  [w5]"v"(w[5]),  [w6]"v"(w[6]),  [w7]"v"(w[7]),
          [w8]"v"(w[8]),  [w9]"v"(w[9]),  [w10]"v"(w[10]),[w11]"v"(w[11]),
          [w12]"v"(w[12]),[w13]"v"(w[13]),[w14]"v"(w[14]),[w15]"v"(w[15]));
}

// Block-end finisher: seed from final r (row t0+15) and reduce. s_nop 1
// covers DPP read-after-write hazards (R8-proven).
__device__ __forceinline__ void finish_reduce(float r, float& p, float& pk,
                                              float wo2, float m15) {
    asm volatile(
        "v_mul_f32 %[p], %[wo2], %[r]\n\t"
        "s_nop 1\n\t"
        "v_add_f32_dpp %[p], %[p], %[p] row_ror:8 row_mask:0xf bank_mask:0xf\n\t"
        "s_nop 1\n\t"
        "v_add_f32_dpp %[p], %[p], %[p] row_ror:4 row_mask:0xf bank_mask:0xf\n\t"
        "s_nop 1\n\t"
        "v_add_f32_dpp %[p], %[p], %[p] row_ror:2 row_mask:0xf bank_mask:0xf\n\t"
        "s_nop 1\n\t"
        "v_add_f32_dpp %[p], %[p], %[p] row_ror:1 row_mask:0xf bank_mask:0xf\n\t"
        "s_nop 1\n\t"
        "v_fmac_f32 %[pk], %[p], %[m]"
        : [p]"+v"(p), [pk]"+v"(pk)
        : [r]"v"(r), [wo2]"v"(wo2), [m]"v"(m15));
}

__global__ __launch_bounds__(64, 1) void rnn_kernel(
    const float* __restrict__ x,
    const float* __restrict__ h0,
    const float* __restrict__ W_ih,
    const float* __restrict__ b_ih,
    const float* __restrict__ W_hh,
    const float* __restrict__ b_hh,
    const float* __restrict__ W_out,
    const float* __restrict__ b_out,
    float* __restrict__ out)
{
    const int tid = threadIdx.x;            // 0..63
    const int j   = tid & 15;               // lane-in-group; j<10 owns dim j
    const int b   = (blockIdx.x << 2) + (tid >> 4);
    const bool jv = (j < HID);
    const int jc  = jv ? j : 0;

    const float CC = 2.88539008177792681472f;   // 2*log2(e)

    // Raw per-lane weights (idle lanes zero).
    const float wih = jv ? W_ih[jc] : 0.0f;
    const float bj  = jv ? (b_ih[jc] + b_hh[jc]) : 0.0f;
    const float wo  = jv ? W_out[jc] : 0.0f;

    float wsh[16];
    float wsum = 0.0f;
#pragma unroll
    for (int N = 0; N < 16; ++N) {
        const int k = (j - N) & 15;
        wsh[N] = (jv && k < HID) ? W_hh[jc * HID + k] : 0.0f;
        wsum += wsh[N];
    }

    // r-form folded constants: a' = C*a with h = 1-2r absorbed.
    const float wih2 = CC * wih;
    const float bj2  = CC * (bj + wsum);
    float w2[16];
#pragma unroll
    for (int N = 0; N < 16; ++N) w2[N] = -2.0f * CC * wsh[N];
    const float wo2 = -2.0f * wo;
    float c0sum = b_out[0];
#pragma unroll
    for (int k = 0; k < HID; ++k) c0sum += W_out[k];   // C0 = sum(wo) + bo

    // Keep-masks.
    float km[16];
#pragma unroll
    for (int i = 0; i < 16; ++i) km[i] = (j == i) ? 1.0f : 0.0f;
    const float mzero = 0.0f;

    // r_0 = (1 - h_0)/2 ; idle lanes h0=0 -> r=0.5 (their fixed point).
    float rval = fmaf(-0.5f, jv ? h0[b * HID + jc] : 0.0f, 0.5f);
    float p = 0.0f, pk = 0.0f;

    const float* xb = x + b;
    float xA[UB], xB[UB];

    issue16(xA, xb);
    wait0_bind(xA);

    for (int t0 = 0; t0 < T_STEPS; t0 += 2 * UB) {
        // ---- half 1: consume xA, prefetch xB ----
        wait1_bind(xA);
        issue16(xB, xb + (size_t)(t0 + UB) * BATCH);
#pragma unroll
        for (int u = 0; u < UB; ++u)
            step_blob(rval, p, pk, xA[u], wih2, bj2, wo2,
                      (u == 0) ? mzero : km[u - 1], w2);
        finish_reduce(rval, p, pk, wo2, km[15]);
        out[(size_t)(t0 + j) * BATCH + b] = pk + c0sum;
        pk = 0.0f;

        // ---- half 2: consume xB, prefetch xA ----
        wait1_bind(xB);
        const float* xsrc = (t0 + 2 * UB < T_STEPS)
                          ? (xb + (size_t)(t0 + 2 * UB) * BATCH) : xb;
        issue16(xA, xsrc);
#pragma unroll
        for (int u = 0; u < UB; ++u)
            step_blob(rval, p, pk, xB[u], wih2, bj2, wo2,
                      (u == 0) ? mzero : km[u - 1], w2);
        finish_reduce(rval, p, pk, wo2, km[15]);
        out[(size_t)(t0 + UB + j) * BATCH + b] = pk + c0sum;
        pk = 0.0f;
    }

    // Drain the final speculative xA reload while registers are still bound
    // (async-clobber hazard, R6 post-mortem).
    wait0_bind(xA);

    // h_last: h = 1 - 2r
    if (jv) out[(size_t)T_STEPS * BATCH + (size_t)b * HID + j]
                = fmaf(-2.0f, rval, 1.0f);
}

extern "C" void kernel_launch(void* const* d_in, const int* in_sizes, int n_in,
                              void* d_out, int out_size, void* d_ws, size_t ws_size,
                              hipStream_t stream) {
    const float* x     = (const float*)d_in[0];
    const float* h0    = (const float*)d_in[1];
    const float* W_ih  = (const float*)d_in[2];
    const float* b_ih  = (const float*)d_in[3];
    const float* W_hh  = (const float*)d_in[4];
    const float* b_hh  = (const float*)d_in[5];
    const float* W_out = (const float*)d_in[6];
    const float* b_out = (const float*)d_in[7];

    rnn_kernel<<<BATCH / 4, 64, 0, stream>>>(
        x, h0, W_ih, b_ih, W_hh, b_hh, W_out, b_out, (float*)d_out);
}